// Round 3
// baseline (16261.145 us; speedup 1.0000x reference)
//
#include <hip/hip_runtime.h>
#include <hip/hip_bf16.h>

typedef _Float16 f16;
typedef _Float16 f16x8 __attribute__((ext_vector_type(8)));
typedef float f32x4 __attribute__((ext_vector_type(4)));

#define T_ 256
#define B_ 64
#define SC 2048.0f
#define INV_SC (1.0f / 2048.0f)

// x (B,T,512,2) fp32 -> X0 [T][4][B][512] f16, seg: 0=r_hi 1=i_hi 2=r_lo(x2048) 3=i_lo(x2048)
__global__ void prepack_x_kernel(const float* __restrict__ x, f16* __restrict__ X0) {
  unsigned int idx = blockIdx.x * 256 + threadIdx.x;  // < 33,554,432
  int k   = idx & 511;
  int m   = (idx >> 9) & 63;
  int seg = (idx >> 15) & 3;
  int t   = idx >> 17;
  int cc = seg & 1, lo = seg >> 1;
  float v = x[(((size_t)m * T_ + t) * 512 + k) * 2 + cc];
  f16 h = (f16)v;
  X0[idx] = lo ? (f16)((v - (float)h) * SC) : h;
}

// Pack weights: out = [Wf | Wlo], each [4096][2048] f16. Wlo scaled by 2048.
//  row 2n   (pre_r col n): [ Wr_i2h[n] | -Wi_i2h[n] |  Wr_h2h[n] | -Wi_h2h[n] ]
//  row 2n+1 (pre_i col n): [ Wi_i2h[n] |  Wr_i2h[n] |  Wi_h2h[n] |  Wr_h2h[n] ]
// EXACTLY 2*4096*2048 = 16,777,216 threads (round-2 bug: 2x overflow trashed
// zeroh/c_state after their memset -> ~0.17 absmax. Grid must be 65536.)
__global__ void prepack_w_kernel(const float* __restrict__ Wri, const float* __restrict__ Wii,
                                 const float* __restrict__ Wrh, const float* __restrict__ Wih,
                                 f16* __restrict__ out) {
  unsigned int idx = blockIdx.x * 256 + threadIdx.x;  // < 16,777,216
  int k2    = idx & 2047;
  int np    = (idx >> 11) & 4095;
  int which = idx >> 23;
  int n = np >> 1, cc = np & 1;
  int kb = k2 >> 9, k = k2 & 511;
  size_t s = (size_t)n * 512 + k;
  float v;
  if (cc == 0) v = (kb == 0) ? Wri[s] : (kb == 1) ? -Wii[s] : (kb == 2) ? Wrh[s] : -Wih[s];
  else         v = (kb == 0) ? Wii[s] : (kb == 1) ?  Wri[s] : (kb == 2) ? Wih[s] :  Wrh[s];
  f16 h = (f16)v;
  out[idx] = which ? (f16)((v - (float)h) * SC) : h;
}

// One recurrent step. Grid 256x256. Block: 16 batch rows x (8 hidden j x 4 gates).
// 3-term compensated GEMM: acc += Wf*a_hi ; sacc += Wf*(a_lo*2^11) + (Wlo*2^11)*a_hi.
__global__ __launch_bounds__(256) void lstm_step(
    const f16* __restrict__ X,       // [T][4][B][512]
    const f16* __restrict__ Hprev,   // [4][B][512]
    f16* __restrict__ Yout,          // [4][B][512]
    float* __restrict__ c_state,     // [B][512][2] fp32 persistent
    const f16* __restrict__ Wp,      // [Wf|Wlo] each [4096][2048]
    const float* __restrict__ br1, const float* __restrict__ bi1,
    const float* __restrict__ br2, const float* __restrict__ bi2,
    float* __restrict__ y_out, float* __restrict__ h_out, float* __restrict__ c_out,
    int t) {
  int bid = blockIdx.x;
  int xcd = bid & 7, rest = bid >> 3;
  int mh = rest & 3, jhi = rest >> 2;
  int jblk = jhi * 8 + xcd;
  int j0 = jblk * 8;
  int m0 = mh * 16;

  int tid = threadIdx.x;
  int w = tid >> 6, l = tid & 63;
  int l15 = l & 15, lg = l >> 4;
  int klane = lg * 8;

  const f16* Xt = X + (size_t)t * (4 * B_ * 512);
  const f16* ahi[4] = {Xt, Xt + 32768, Hprev, Hprev + 32768};
  const f16* alo[4] = {Xt + 65536, Xt + 98304, Hprev + 65536, Hprev + 98304};
  int aoff = (m0 + l15) * 512 + klane;

  const f16* bf = Wp + (size_t)((w * 512 + j0) * 2 + l15) * 2048 + klane;
  const f16* bl = bf + 8388608;

  f32x4 acc0 = {0.f, 0.f, 0.f, 0.f}, acc1 = {0.f, 0.f, 0.f, 0.f};
  f32x4 sacc0 = {0.f, 0.f, 0.f, 0.f}, sacc1 = {0.f, 0.f, 0.f, 0.f};

#pragma unroll
  for (int seg = 0; seg < 4; ++seg) {
    const f16* ah = ahi[seg] + aoff;
    const f16* al = alo[seg] + aoff;
    const f16* bfp = bf + seg * 512;
    const f16* blp = bl + seg * 512;
#pragma unroll
    for (int kk = 0; kk < 16; kk += 2) {
      f16x8 a0 = *reinterpret_cast<const f16x8*>(ah + kk * 32);
      f16x8 a1 = *reinterpret_cast<const f16x8*>(ah + kk * 32 + 32);
      f16x8 l0 = *reinterpret_cast<const f16x8*>(al + kk * 32);
      f16x8 l1 = *reinterpret_cast<const f16x8*>(al + kk * 32 + 32);
      f16x8 b0 = *reinterpret_cast<const f16x8*>(bfp + kk * 32);
      f16x8 b1 = *reinterpret_cast<const f16x8*>(bfp + kk * 32 + 32);
      f16x8 c0 = *reinterpret_cast<const f16x8*>(blp + kk * 32);
      f16x8 c1 = *reinterpret_cast<const f16x8*>(blp + kk * 32 + 32);
      acc0  = __builtin_amdgcn_mfma_f32_16x16x32_f16(a0, b0, acc0, 0, 0, 0);
      acc1  = __builtin_amdgcn_mfma_f32_16x16x32_f16(a1, b1, acc1, 0, 0, 0);
      sacc0 = __builtin_amdgcn_mfma_f32_16x16x32_f16(l0, b0, sacc0, 0, 0, 0);
      sacc1 = __builtin_amdgcn_mfma_f32_16x16x32_f16(l1, b1, sacc1, 0, 0, 0);
      sacc0 = __builtin_amdgcn_mfma_f32_16x16x32_f16(a0, c0, sacc0, 0, 0, 0);
      sacc1 = __builtin_amdgcn_mfma_f32_16x16x32_f16(a1, c1, sacc1, 0, 0, 0);
    }
  }
  f32x4 accm = acc0 + acc1;
  f32x4 accs = sacc0 + sacc1;
  f32x4 acc = accm + accs * INV_SC;

  __shared__ float lds[16][65];
#pragma unroll
  for (int r = 0; r < 4; ++r)
    lds[lg * 4 + r][w * 16 + l15] = acc[r];
  __syncthreads();

  if (tid < 128) {
    int ml = tid >> 3, jj = tid & 7;
    int mg = m0 + ml;
    int jg = j0 + jj;

    float zr[4], zi[4];
#pragma unroll
    for (int gg = 0; gg < 4; ++gg) {
      int n = gg * 512 + jg;
      zr[gg] = lds[ml][gg * 16 + 2 * jj]     + br1[n] + br2[n];
      zi[gg] = lds[ml][gg * 16 + 2 * jj + 1] + bi1[n] + bi2[n];
    }
    float gr[4], gi[4];
#pragma unroll
    for (int gg = 0; gg < 4; ++gg) {
      float mag = sqrtf(zr[gg] * zr[gg] + zi[gg] * zi[gg]);
      float fn = (gg < 3) ? (1.f / (1.f + __expf(-mag))) : tanhf(mag);
      float s = fn / (mag + 1e-8f);
      gr[gg] = zr[gg] * s;
      gi[gg] = zi[gg] * s;
    }
    float* cp = c_state + ((size_t)mg * 512 + jg) * 2;
    float cr = cp[0], ci = cp[1];
    float cnr = cr * gr[1] + gr[0] * gr[3];
    float cni = ci * gi[1] + gi[0] * gi[3];
    cp[0] = cnr; cp[1] = cni;
    float mm = sqrtf(cnr * cnr + cni * cni);
    float s = tanhf(mm) / (mm + 1e-8f);
    float dr = cnr * s, di = cni * s;
    float hr = gr[2] * dr - gi[2] * di;
    float hi = gi[2] * dr + gr[2] * di;

    int o = mg * 512 + jg;
    f16 hrh = (f16)hr, hih = (f16)hi;
    Yout[o]         = hrh;
    Yout[32768 + o] = hih;
    Yout[65536 + o] = (f16)((hr - (float)hrh) * SC);
    Yout[98304 + o] = (f16)((hi - (float)hih) * SC);
    if (y_out) {
      float* yp = y_out + (((size_t)mg * T_ + t) * 512 + jg) * 2;
      yp[0] = hr; yp[1] = hi;
    }
    if (h_out) {
      float* hp = h_out + ((size_t)mg * 512 + jg) * 2;
      hp[0] = hr; hp[1] = hi;
      float* cq = c_out + ((size_t)mg * 512 + jg) * 2;
      cq[0] = cnr; cq[1] = cni;
    }
  }
}

extern "C" void kernel_launch(void* const* d_in, const int* in_sizes, int n_in,
                              void* d_out, int out_size, void* d_ws, size_t ws_size,
                              hipStream_t stream) {
  const float* x = (const float*)d_in[0];
  char* ws = (char*)d_ws;
  // ws layout (bytes):
  f16* X0    = (f16*)(ws + 0);                     //  64 MB [T][4][B][512]
  f16* ys0   = (f16*)(ws + (size_t)67108864);      //  64 MB layer0 h history
  f16* W0    = (f16*)(ws + (size_t)134217728);     //  32 MB [Wf0|Wlo0]
  f16* W1    = (f16*)(ws + (size_t)167772160);     //  32 MB [Wf1|Wlo1]
  f16* ys1   = (f16*)(ws + (size_t)201326592);     // 512 KB: 2 slots x [4][B][512]
  f16* zeroh = (f16*)(ws + (size_t)201850880);     // 256 KB zeros
  float* cst = (float*)(ws + (size_t)202113024);   //   1 MB c-state, 2 layers

  hipMemsetAsync(ws + 201850880, 0, 262144 + 1048576, stream);

  prepack_x_kernel<<<131072, 256, 0, stream>>>(x, X0);
  prepack_w_kernel<<<65536, 256, 0, stream>>>((const float*)d_in[1], (const float*)d_in[2],
                                              (const float*)d_in[5], (const float*)d_in[6], W0);
  prepack_w_kernel<<<65536, 256, 0, stream>>>((const float*)d_in[9], (const float*)d_in[10],
                                              (const float*)d_in[13], (const float*)d_in[14], W1);

  float* y    = (float*)d_out;
  float* hout = y + 16777216;
  float* cout = hout + 131072;

  for (int t = 0; t < T_; ++t) {
    const f16* hp = (t == 0) ? zeroh : (ys0 + (size_t)(t - 1) * 131072);
    lstm_step<<<256, 256, 0, stream>>>(X0, hp, ys0 + (size_t)t * 131072, cst, W0,
        (const float*)d_in[3], (const float*)d_in[4],
        (const float*)d_in[7], (const float*)d_in[8],
        nullptr,
        (t == T_ - 1) ? hout : nullptr,
        (t == T_ - 1) ? cout : nullptr,
        t);
  }
  for (int t = 0; t < T_; ++t) {
    const f16* hp = (t == 0) ? zeroh : (ys1 + (size_t)((t - 1) & 1) * 131072);
    lstm_step<<<256, 256, 0, stream>>>(ys0, hp, ys1 + (size_t)(t & 1) * 131072, cst + 65536, W1,
        (const float*)d_in[11], (const float*)d_in[12],
        (const float*)d_in[15], (const float*)d_in[16],
        y,
        (t == T_ - 1) ? (hout + 65536) : nullptr,
        (t == T_ - 1) ? (cout + 65536) : nullptr,
        t);
  }
}

// Round 4
// 9278.925 us; speedup vs baseline: 1.7525x; 1.7525x over previous
//
#include <hip/hip_runtime.h>
#include <hip/hip_bf16.h>

typedef _Float16 f16;
typedef _Float16 f16x8 __attribute__((ext_vector_type(8)));
typedef float f32x4 __attribute__((ext_vector_type(4)));

#define T_ 256
#define B_ 64
#define SC 2048.0f
#define INV_SC (1.0f / 2048.0f)

// ---------------------------------------------------------------------------
// Fragment layouts (all f16):
//   A-buffers (x or h): [mt 4][ks 32][part 2][lane 64][e 8]   (256 KB / step)
//     element = A[mt*16 + (lane&15)][ks*32 + (lane>>4)*8 + e], part 0=hi 1=lo*SC
//     x-buffer k: 0..511 = xr, 512..1023 = xi
//     h-buffer k: 0..511 = hr, 512..1023 = h_imag
//   W-buffer: [nblk 256][ks 64][part 2][lane 64][e 8]          (32 MB / layer)
//     row n' = nblk*16 + (lane&15), n' = (j*4+g)*2+cc  (j-major!)
//     k = ks*32 + (lane>>4)*8 + e over [xr|xi|hr|hi] segments of 512
// ---------------------------------------------------------------------------

// x (B,T,512,2) fp32 -> X0 [T][mt][ks32][part][512] f16
__global__ void prepack_x_kernel(const float* __restrict__ x, f16* __restrict__ X0) {
  unsigned int idx = blockIdx.x * 256 + threadIdx.x;  // < 33,554,432
  int e    = idx & 7;
  int l    = (idx >> 3) & 63;
  int part = (idx >> 9) & 1;
  int ks   = (idx >> 10) & 31;
  int mt   = (idx >> 15) & 3;
  int t    = idx >> 17;
  int m = mt * 16 + (l & 15);
  int k = ks * 32 + ((l >> 4) << 3) + e;   // 0..1023
  int cc = k >> 9, kw = k & 511;
  float v = x[(((size_t)m * T_ + t) * 512 + kw) * 2 + cc];
  f16 h = (f16)v;
  X0[idx] = part ? (f16)((v - (float)h) * SC) : h;
}

// Weights -> fragment-ordered packed W (j-major rows). 16,777,216 threads.
__global__ void prepack_w_kernel(const float* __restrict__ Wri, const float* __restrict__ Wii,
                                 const float* __restrict__ Wrh, const float* __restrict__ Wih,
                                 f16* __restrict__ out) {
  unsigned int idx = blockIdx.x * 256 + threadIdx.x;  // < 16,777,216
  int e    = idx & 7;
  int l    = (idx >> 3) & 63;
  int part = (idx >> 9) & 1;
  int ks   = (idx >> 10) & 63;
  int nblk = idx >> 16;
  int np = nblk * 16 + (l & 15);          // n' = (j*4+g)*2+cc
  int k  = ks * 32 + ((l >> 4) << 3) + e; // 0..2047
  int j  = np >> 3;
  int g  = (np >> 1) & 3;
  int cc = np & 1;
  int kb = k >> 9, kw = k & 511;
  size_t s = (size_t)(g * 512 + j) * 512 + kw;
  float v;
  if (cc == 0) v = (kb == 0) ? Wri[s] : (kb == 1) ? -Wii[s] : (kb == 2) ? Wrh[s] : -Wih[s];
  else         v = (kb == 0) ? Wii[s] : (kb == 1) ?  Wri[s] : (kb == 2) ? Wih[s] :  Wrh[s];
  f16 h = (f16)v;
  out[idx] = part ? (f16)((v - (float)h) * SC) : h;
}

// One recurrent step. Grid 256 blocks x 512 threads.
// Block = full batch (M=64) x 2 hidden j (N=16: 2j x 4 gates x r/i).
// 8 waves = 4 m-tiles x 2 K-halves (kh=0: x-part ks0..31, kh=1: h-part).
__global__ __launch_bounds__(512) void lstm_step(
    const f16* __restrict__ Ax,      // x-part frags [mt][32][2][512]
    const f16* __restrict__ Ah,      // h-part frags, same layout
    f16* __restrict__ Yfrag,         // h_t output, same layout
    float* __restrict__ c_state,     // [B][512][2] fp32 persistent
    const f16* __restrict__ W,       // [nblk][64][2][512]
    const float* __restrict__ br1, const float* __restrict__ bi1,
    const float* __restrict__ br2, const float* __restrict__ bi2,
    float* __restrict__ y_out, float* __restrict__ h_out, float* __restrict__ c_out,
    int t) {
  int nblk = blockIdx.x;
  int tid = threadIdx.x;
  int w = tid >> 6, l = tid & 63;
  int mt = w & 3, kh = w >> 2;

  const f16* pa = (kh ? Ah : Ax) + mt * 32768 + l * 8;
  const f16* pb = W + (size_t)nblk * 65536 + kh * 32768 + l * 8;

  f32x4 acc = {0.f, 0.f, 0.f, 0.f}, sacc = {0.f, 0.f, 0.f, 0.f};
#pragma unroll 8
  for (int ks = 0; ks < 32; ++ks) {
    f16x8 ah = *reinterpret_cast<const f16x8*>(pa + ks * 1024);
    f16x8 al = *reinterpret_cast<const f16x8*>(pa + ks * 1024 + 512);
    f16x8 bh = *reinterpret_cast<const f16x8*>(pb + ks * 1024);
    f16x8 bl = *reinterpret_cast<const f16x8*>(pb + ks * 1024 + 512);
    acc  = __builtin_amdgcn_mfma_f32_16x16x32_f16(ah, bh, acc, 0, 0, 0);
    sacc = __builtin_amdgcn_mfma_f32_16x16x32_f16(al, bh, sacc, 0, 0, 0);
    sacc = __builtin_amdgcn_mfma_f32_16x16x32_f16(ah, bl, sacc, 0, 0, 0);
  }
  f32x4 comb = acc + sacc * INV_SC;

  // C-layout: col = l&15 (n_local), row = (l>>4)*4 + r (m within tile)
  __shared__ float lds[2][4][16][17];
  int n_loc = l & 15, r0 = (l >> 4) * 4;
#pragma unroll
  for (int r = 0; r < 4; ++r) lds[kh][mt][n_loc][r0 + r] = comb[r];
  __syncthreads();

  if (tid < 128) {
    int m = tid >> 1, jl = tid & 1;
    int jg = nblk * 2 + jl;
    int mtt = m >> 4, ml = m & 15;

    float zr[4], zi[4];
#pragma unroll
    for (int g = 0; g < 4; ++g) {
      int nr = jl * 8 + g * 2, ni = nr + 1;
      int nb = g * 512 + jg;
      zr[g] = lds[0][mtt][nr][ml] + lds[1][mtt][nr][ml] + br1[nb] + br2[nb];
      zi[g] = lds[0][mtt][ni][ml] + lds[1][mtt][ni][ml] + bi1[nb] + bi2[nb];
    }
    float gr[4], gi[4];
#pragma unroll
    for (int g = 0; g < 4; ++g) {
      float mag = sqrtf(zr[g] * zr[g] + zi[g] * zi[g]);
      float fn = (g < 3) ? (1.f / (1.f + __expf(-mag))) : tanhf(mag);
      float s = fn / (mag + 1e-8f);
      gr[g] = zr[g] * s;
      gi[g] = zi[g] * s;
    }
    float* cp = c_state + ((size_t)m * 512 + jg) * 2;
    float cr = cp[0], ci = cp[1];
    float cnr = cr * gr[1] + gr[0] * gr[3];
    float cni = ci * gi[1] + gi[0] * gi[3];
    cp[0] = cnr; cp[1] = cni;
    float mm = sqrtf(cnr * cnr + cni * cni);
    float s = tanhf(mm) / (mm + 1e-8f);
    float dr = cnr * s, di = cni * s;
    float hr = gr[2] * dr - gi[2] * di;
    float him = gi[2] * dr + gr[2] * di;

    // h -> fragment layout: hr at k'=jg, h_imag at k'=512+jg
    int lane_h = ((jg >> 3) & 3) * 16 + ml;
    int ksr = jg >> 5;
    size_t basef = (size_t)mtt * 32768 + (size_t)lane_h * 8 + (jg & 7);
    f16 hrh = (f16)hr, hih = (f16)him;
    Yfrag[basef + (size_t)(ksr * 2 + 0) * 512]        = hrh;
    Yfrag[basef + (size_t)(ksr * 2 + 1) * 512]        = (f16)((hr - (float)hrh) * SC);
    Yfrag[basef + (size_t)((16 + ksr) * 2 + 0) * 512] = hih;
    Yfrag[basef + (size_t)((16 + ksr) * 2 + 1) * 512] = (f16)((him - (float)hih) * SC);

    if (y_out) {
      float* yp = y_out + (((size_t)m * T_ + t) * 512 + jg) * 2;
      yp[0] = hr; yp[1] = him;
    }
    if (h_out) {
      float* hp = h_out + ((size_t)m * 512 + jg) * 2;
      hp[0] = hr; hp[1] = him;
      float* cq = c_out + ((size_t)m * 512 + jg) * 2;
      cq[0] = cnr; cq[1] = cni;
    }
  }
}

extern "C" void kernel_launch(void* const* d_in, const int* in_sizes, int n_in,
                              void* d_out, int out_size, void* d_ws, size_t ws_size,
                              hipStream_t stream) {
  const float* x = (const float*)d_in[0];
  char* ws = (char*)d_ws;
  // ws layout (bytes):
  f16* X0    = (f16*)(ws + 0);                     //  64 MB [T] x 256KB x-frags
  f16* ys0   = (f16*)(ws + (size_t)67108864);      //  64 MB layer0 h frags (= layer1 x)
  f16* W0    = (f16*)(ws + (size_t)134217728);     //  32 MB
  f16* W1    = (f16*)(ws + (size_t)167772160);     //  32 MB
  f16* ys1   = (f16*)(ws + (size_t)201326592);     // 512 KB: 2 slots
  f16* zeroF = (f16*)(ws + (size_t)201850880);     // 256 KB zeros
  float* cst = (float*)(ws + (size_t)202113024);   // 512 KB c-state, 2 layers

  hipMemsetAsync(ws + 201850880, 0, 262144 + 524288, stream);

  prepack_x_kernel<<<131072, 256, 0, stream>>>(x, X0);
  prepack_w_kernel<<<65536, 256, 0, stream>>>((const float*)d_in[1], (const float*)d_in[2],
                                              (const float*)d_in[5], (const float*)d_in[6], W0);
  prepack_w_kernel<<<65536, 256, 0, stream>>>((const float*)d_in[9], (const float*)d_in[10],
                                              (const float*)d_in[13], (const float*)d_in[14], W1);

  float* y    = (float*)d_out;
  float* hout = y + 16777216;
  float* cout = hout + 131072;

  for (int t = 0; t < T_; ++t) {
    const f16* hp = (t == 0) ? zeroF : (ys0 + (size_t)(t - 1) * 131072);
    lstm_step<<<256, 512, 0, stream>>>(X0 + (size_t)t * 131072, hp,
        ys0 + (size_t)t * 131072, cst, W0,
        (const float*)d_in[3], (const float*)d_in[4],
        (const float*)d_in[7], (const float*)d_in[8],
        nullptr,
        (t == T_ - 1) ? hout : nullptr,
        (t == T_ - 1) ? cout : nullptr,
        t);
  }
  for (int t = 0; t < T_; ++t) {
    const f16* hp = (t == 0) ? zeroF : (ys1 + (size_t)((t - 1) & 1) * 131072);
    lstm_step<<<256, 512, 0, stream>>>(ys0 + (size_t)t * 131072, hp,
        ys1 + (size_t)(t & 1) * 131072, cst + 65536, W1,
        (const float*)d_in[11], (const float*)d_in[12],
        (const float*)d_in[15], (const float*)d_in[16],
        y,
        (t == T_ - 1) ? (hout + 65536) : nullptr,
        (t == T_ - 1) ? (cout + 65536) : nullptr,
        t);
  }
}